// Round 1
// baseline (441.981 us; speedup 1.0000x reference)
//
#include <hip/hip_runtime.h>

// HebbLinear fused kernel, round 3.
// y[b,o] = sum_i x[b,i]*w[i,o] + (x[b,i]*alpha[i])*hebb[b,i,o] + bias[o]
// delta[b,i,o] = x[b,i]*y[b,o]
// out = [ y (256*512) | delta (256*512*512) ] flat f32.
//
// HBM floor: hebb read 268 MB + delta write 268 MB ~ 83 us @ 6.48 TB/s.
// R3 change vs R2: split the o-dimension across 2 blocks per batch row
// (grid 512 x 256 threads, 2 blocks/CU) so each CU holds two independent
// blocks at different phases -- one block's hebb read overlaps the
// other's reduce/delta write, hiding the phase-transition drain that a
// 1-block/CU launch serializes. Coalescing unchanged: each wave still
// reads/writes 1 KB contiguous per row-stripe. Nontemporal kept on the
// zero-reuse streams (hebb in, y/delta out); w/bias stay L2-resident.

typedef float v4f __attribute__((ext_vector_type(4)));
typedef float v2f __attribute__((ext_vector_type(2)));

#define IND   512
#define OUTD  512
#define BSZ   256
#define ROWQ  (OUTD / 4)   // 128 float4 per full o-row
#define OHALF 256          // o-columns per block
#define OQ2   (OHALF / 4)  // 64 float4 groups per block

__global__ __launch_bounds__(256, 2) void hebb_fused(
    const float* __restrict__ x,
    const float* __restrict__ hebb,
    const float* __restrict__ w,
    const float* __restrict__ bias,
    const float* __restrict__ alpha,
    float* __restrict__ out)
{
    const int b   = blockIdx.x >> 1;   // batch row
    const int oh  = blockIdx.x & 1;    // which o-half
    const int tid = threadIdx.x;
    const int oq  = tid & (OQ2 - 1);   // float4 index within the o-stripe, 0..63
    const int ip  = tid >> 6;          // i-phase 0..3 (== wave id)

    __shared__ v2f x2_s[IND];          // {x[i], x[i]*alpha[i]}
    __shared__ v4f red_s[4][OQ2];      // 4 KB partial-sum exchange
    __shared__ v4f y_s[OQ2];           // final y stripe for phase 2

    // Stage x and x*alpha (256 threads, 2 elems each)
    {
        const float xv0 = x[b * IND + tid];
        const float xv1 = x[b * IND + tid + 256];
        v2f t0; t0.x = xv0; t0.y = xv0 * alpha[tid];
        v2f t1; t1.x = xv1; t1.y = xv1 * alpha[tid + 256];
        x2_s[tid]       = t0;
        x2_s[tid + 256] = t1;
    }
    __syncthreads();

    const v4f* __restrict__ hb4 = (const v4f*)hebb
                                + (size_t)b * (IND * ROWQ) + oh * OQ2;
    const v4f* __restrict__ w4  = (const v4f*)w + oh * OQ2;

    // Phase 1: batched GEMV over this block's 256-column stripe.
    // hebb is a zero-reuse HBM stream -> nontemporal; w reused by all
    // blocks -> normal (L2-resident). Wave = 64 lanes x 16 B = 1 KB
    // contiguous per row-stripe access.
    v4f acc = 0.0f;
#pragma unroll 8
    for (int i = ip; i < IND; i += 4) {
        const v2f xx = x2_s[i];        // ds_read_b64, same-addr broadcast
        const v4f wv = w4[i * ROWQ + oq];
        const v4f hv = __builtin_nontemporal_load(&hb4[i * ROWQ + oq]);
        acc += xx.x * wv + xx.y * hv;  // contracts to v_fma_f32
    }
    red_s[ip][oq] = acc;
    __syncthreads();

    // Reduce 4 i-phases, add bias, emit y stripe
    if (ip == 0) {
        v4f y = (red_s[0][oq] + red_s[1][oq]) + (red_s[2][oq] + red_s[3][oq])
              + ((const v4f*)bias)[oh * OQ2 + oq];
        y_s[oq] = y;
        __builtin_nontemporal_store(y, (v4f*)out + b * ROWQ + oh * OQ2 + oq);
    }
    __syncthreads();

    // Phase 2: delta[b,i,o] = x[i]*y[o] -- zero-reuse write, nontemporal
    const v4f y = y_s[oq];
    v4f* __restrict__ delta4 = (v4f*)(out + BSZ * OUTD)
                             + (size_t)b * (IND * ROWQ) + oh * OQ2;
#pragma unroll 8
    for (int i = ip; i < IND; i += 4) {
        __builtin_nontemporal_store(x2_s[i].x * y, &delta4[i * ROWQ + oq]);
    }
}

extern "C" void kernel_launch(void* const* d_in, const int* in_sizes, int n_in,
                              void* d_out, int out_size, void* d_ws, size_t ws_size,
                              hipStream_t stream)
{
    const float* x     = (const float*)d_in[0];
    const float* hebb  = (const float*)d_in[1];
    const float* w     = (const float*)d_in[2];
    const float* bias  = (const float*)d_in[3];
    const float* alpha = (const float*)d_in[4];
    float* out = (float*)d_out;

    hipLaunchKernelGGL(hebb_fused, dim3(BSZ * 2), dim3(256), 0, stream,
                       x, hebb, w, bias, alpha, out);
}

// Round 2
// 428.027 us; speedup vs baseline: 1.0326x; 1.0326x over previous
//
#include <hip/hip_runtime.h>

// HebbLinear fused kernel, round 4.
// y[b,o] = sum_i x[b,i]*w[i,o] + (x[b,i]*alpha[i])*hebb[b,i,o] + bias[o]
// delta[b,i,o] = x[b,i]*y[b,o]
// out = [ y (256*512) | delta (256*512*512) ] flat f32.
//
// HBM floor: hebb read 268 MB + delta write 268 MB ~ 83-85 us @ 6.3-6.5 TB/s.
// R4 = R2 structure (R3's o-split broke stream contiguity and regressed:
// 1 KB stripe + 2 KB jump loses DRAM row locality -- reverted).
// Change vs R2: redundant reduction. After the single barrier, EVERY
// thread reads red_s[0..3][oq] and computes its own y -- removes y_s,
// the ip==0-only reduce bubble (6 of 8 waves idle), and the second
// __syncthreads() full-CU drain between read phase and write phase.
// Numerics identical (same pairwise reduce order).

typedef float v4f __attribute__((ext_vector_type(4)));
typedef float v2f __attribute__((ext_vector_type(2)));

#define IND  512
#define OUTD 512
#define BSZ  256
#define OQ   (OUTD / 4)   // 128 float4 groups along o

__global__ __launch_bounds__(512, 2) void hebb_fused(
    const float* __restrict__ x,
    const float* __restrict__ hebb,
    const float* __restrict__ w,
    const float* __restrict__ bias,
    const float* __restrict__ alpha,
    float* __restrict__ out)
{
    const int b   = blockIdx.x;
    const int tid = threadIdx.x;
    const int oq  = tid & (OQ - 1);   // float4 index along o
    const int ip  = tid >> 7;         // i-phase 0..3

    __shared__ v2f x2_s[IND];         // {x[i], x[i]*alpha[i]}
    __shared__ v4f red_s[4][OQ];      // 8 KB partial-sum exchange

    // Stage x and x*alpha (512 threads, 1 elem each)
    {
        const float xv = x[b * IND + tid];
        v2f t;
        t.x = xv;
        t.y = xv * alpha[tid];
        x2_s[tid] = t;
    }
    __syncthreads();

    const v4f* __restrict__ hb4 = (const v4f*)hebb + (size_t)b * (IND * OQ);
    const v4f* __restrict__ w4  = (const v4f*)w;

    // Phase 1: batched GEMV. hebb is a zero-reuse HBM stream -> nontemporal;
    // w is reused by all 256 blocks -> normal (L2-resident). Wave reads
    // 1 KB contiguous per row; block sweeps the full 1 MB slice in order.
    v4f acc = 0.0f;
#pragma unroll 8
    for (int i = ip; i < IND; i += 4) {
        const v2f xx = x2_s[i];       // one ds_read_b64, same-addr broadcast
        const v4f wv = w4[i * OQ + oq];
        const v4f hv = __builtin_nontemporal_load(&hb4[i * OQ + oq]);
        acc += xx.x * wv + xx.y * hv; // contracts to v_fma_f32
    }
    red_s[ip][oq] = acc;
    __syncthreads();

    // Redundant reduce: all 8 waves compute y for their oq directly from
    // red_s (4x ds_read_b128, ~4 KB/wave -- cheap). No y_s, no 2nd barrier.
    const v4f y = (red_s[0][oq] + red_s[1][oq]) + (red_s[2][oq] + red_s[3][oq])
                + ((const v4f*)bias)[oq];
    if (ip == 0) {
        __builtin_nontemporal_store(y, (v4f*)out + b * OQ + oq);
    }

    // Phase 2: delta[b,i,o] = x[i]*y[o] -- zero-reuse write stream,
    // nontemporal, starts immediately per-thread (no barrier).
    v4f* __restrict__ delta4 = (v4f*)(out + BSZ * OUTD) + (size_t)b * (IND * OQ);
#pragma unroll 8
    for (int i = ip; i < IND; i += 4) {
        const float xs = x2_s[i].x;
        __builtin_nontemporal_store(xs * y, &delta4[i * OQ + oq]);
    }
}

extern "C" void kernel_launch(void* const* d_in, const int* in_sizes, int n_in,
                              void* d_out, int out_size, void* d_ws, size_t ws_size,
                              hipStream_t stream)
{
    const float* x     = (const float*)d_in[0];
    const float* hebb  = (const float*)d_in[1];
    const float* w     = (const float*)d_in[2];
    const float* bias  = (const float*)d_in[3];
    const float* alpha = (const float*)d_in[4];
    float* out = (float*)d_out;

    hipLaunchKernelGGL(hebb_fused, dim3(BSZ), dim3(512), 0, stream,
                       x, hebb, w, bias, alpha, out);
}